// Round 12
// baseline (124.273 us; speedup 1.0000x reference)
//
#include <hip/hip_runtime.h>
#include <hip/hip_bf16.h>

#define B_ 4
#define T_ 256
#define S_ 256
#define D_ 512
#define TB 2   // t's per attention block

typedef __bf16 bf16x8 __attribute__((ext_vector_type(8)));
typedef float  floatx4 __attribute__((ext_vector_type(4)));

#define C2F 2.885390081777926f  // 2*log2(e)

static __device__ __forceinline__ unsigned short f2bf(float x) {
    __hip_bfloat16 h = __float2bfloat16(x);
    return *reinterpret_cast<unsigned short*>(&h);
}
static __device__ __forceinline__ float asf(unsigned int u) {
    float f; __builtin_memcpy(&f, &u, 4); return f;
}

// ---------------------------------------------------------------------------
// convk: fp32 -> bf16 conversion of all GEMM inputs (one dispatch, 5 z-slices:
// output, context, Wq, Wc, Wout). 18 MB of traffic; halves gemm4b's 128 MB
// LLC-bound re-read stream to 64 MB.
// ---------------------------------------------------------------------------
struct CV { const float* src; unsigned short* dst; int n; };

__global__ __launch_bounds__(256) void convk(CV c0, CV c1, CV c2, CV c3, CV c4)
{
    const int z = blockIdx.z;
    CV c = (z == 0) ? c0 : (z == 1) ? c1 : (z == 2) ? c2 : (z == 3) ? c3 : c4;
    int i = (blockIdx.x * 256 + threadIdx.x) * 4;
    if (i >= c.n) return;
    float4 v = *(const float4*)(c.src + i);
    ushort4 p;
    p.x = f2bf(v.x); p.y = f2bf(v.y); p.z = f2bf(v.z); p.w = f2bf(v.w);
    *(ushort4*)(c.dst + i) = p;
}

// ---------------------------------------------------------------------------
// gemm4b: MFMA GEMM from bf16 inputs. 512 blocks x 1024 threads (16 waves),
// 2 blocks/CU. One 64m x 64n x K=512 tile per block; bid = z + 4*(nblk +
// 8*mblk). Four z-slices:
//   z0: wqs = C2*(output@Wq + bq)            fp32
//   z1: uhb = bf16 C2*(context@Wc)           [b][d/8][s][8]
//   z2: OB  = output@Wout[512:] + bout       fp32
//   z3: CWb = bf16 context@Wout[:512]        natural [row][col]
// K-loop: 16 chunks of 32; bf16 loaded (A: packed pair/thread, W: two
// n-coalesced rows/thread), staged in LDS in MFMA fragment order; each wave
// owns one 16x16 frag -> 2 ds_read_b128 + 1 MFMA per chunk.
// ---------------------------------------------------------------------------
struct G4 {
    const unsigned short* A;   // (1024, 512) bf16 activations
    const unsigned short* W;   // (k, n) bf16, n-stride 512
    int krow0;
    const float* aux;          // bias (fp32) or null
    void* C;
    int mode;
};

__global__ __launch_bounds__(1024, 8) void gemm4b(G4 g0, G4 g1, G4 g2, G4 g3)
{
    const int tid = threadIdx.x;
    const int bid = blockIdx.x;

    const int z  = bid & 3;
    const int n0 = ((bid >> 2) & 7) * 64;
    const int m0 = (bid >> 5) * 64;

    G4 g = (z == 0) ? g0 : (z == 1) ? g1 : (z == 2) ? g2 : g3;

    __shared__ unsigned short Af[4 * 64 * 8];  // 4 KB, frag order
    __shared__ unsigned short Bf[4 * 64 * 8];  // 4 KB, frag order

    // staging: A chunk 64m x 32k, B chunk 32k x 64n; 2 bf16/thread each
    const int am = tid >> 4;              // 0..63
    const int ak = (tid & 15) * 2;        // 0..30 even
    const int bn = tid & 63;
    const int bk = (tid >> 6) * 2;        // 0..30 even

    const unsigned short* Aptr = g.A + (size_t)(m0 + am) * 512 + ak;
    const unsigned short* Wptr = g.W + (size_t)(g.krow0 + bk) * 512 + n0 + bn;

    unsigned int* Awr = (unsigned int*)&Af[((am >> 4) * 64
                          + ((am & 15) | ((ak >> 3) << 4))) * 8 + (ak & 7)];
    unsigned int* Bwr = (unsigned int*)&Bf[((bn >> 4) * 64
                          + ((bn & 15) | ((bk >> 3) << 4))) * 8 + (bk & 7)];

    const int wave = tid >> 6, lane = tid & 63;
    const int l15 = lane & 15, quad = lane >> 4;
    const int mf = wave >> 2, nf = wave & 3;
    const unsigned short* Ard = &Af[(mf * 64 + lane) * 8];
    const unsigned short* Brd = &Bf[(nf * 64 + lane) * 8];

    floatx4 acc = (floatx4){0.f, 0.f, 0.f, 0.f};

    for (int chunk = 0; chunk < 16; ++chunk) {
        const int k0 = chunk * 32;
        unsigned int av = *(const unsigned int*)(Aptr + k0);  // 2 bf16 packed
        unsigned int b0 = Wptr[(size_t)k0 * 512];             // row bk
        unsigned int b1 = Wptr[(size_t)k0 * 512 + 512];       // row bk+1

        __syncthreads();   // prev chunk's frag reads done
        *Awr = av;
        *Bwr = b0 | (b1 << 16);
        __syncthreads();

        bf16x8 fa = *(const bf16x8*)Ard;
        bf16x8 fb = *(const bf16x8*)Brd;
        acc = __builtin_amdgcn_mfma_f32_16x16x32_bf16(fa, fb, acc, 0, 0, 0);
    }

    const int col = n0 + nf * 16 + l15;
    const int rbase = m0 + mf * 16 + quad * 4;
    if (g.mode == 3) {
        unsigned short* Cb = (unsigned short*)g.C;
        #pragma unroll
        for (int r = 0; r < 4; ++r) {
            int row = rbase + r, bb = row >> 8, ss = row & 255;
            Cb[((size_t)(bb * 64 + (col >> 3)) * 256 + ss) * 8 + (col & 7)]
                = f2bf(C2F * acc[r]);
        }
    } else if (g.mode == 5) {
        unsigned short* Cb = (unsigned short*)g.C;
        #pragma unroll
        for (int r = 0; r < 4; ++r)
            Cb[(size_t)(rbase + r) * 512 + col] = f2bf(acc[r]);
    } else {
        float* Cf = (float*)g.C;
        float bv = g.aux ? g.aux[col] : 0.0f;
        #pragma unroll
        for (int r = 0; r < 4; ++r) {
            float val = acc[r] + bv;
            if (g.mode == 1) val *= C2F;
            Cf[(size_t)(rbase + r) * 512 + col] = val;
        }
    }
}

// ---------------------------------------------------------------------------
// Fused score + masked softmax + out-projection (R8 structure; 4-acc ILP).
// 1024 threads; 512 blocks. Thread (s=tid&255, h=tid>>8) owns d-quarter.
// p = exp2(-C2F*A) (shift-invariant softmax; no max reduction).
// ---------------------------------------------------------------------------
__global__ __launch_bounds__(1024) void attn_fused(
    const float* __restrict__ wqs,            // (B,T,D) pre-scaled fp32
    const unsigned short* __restrict__ uhb,   // (B,D/8,S,8) pre-scaled bf16
    const unsigned short* __restrict__ CWb,   // (B,S,D) bf16
    const float* __restrict__ OB,             // (B,T,D) fp32
    const int*   __restrict__ mask,           // (B,S)
    const float* __restrict__ v,              // (D)
    float* __restrict__ attn_out,             // (B,T,S) fp32
    float* __restrict__ out)                  // (B,T,D) fp32
{
    const int bg  = blockIdx.x;
    const int b   = bg / (T_ / TB);
    const int t0  = (bg % (T_ / TB)) * TB;
    const int tid = threadIdx.x;
    const int s   = tid & 255;
    const int h   = tid >> 8;    // 0..3

    __shared__ float  w_s[TB][D_];       // 4 KB
    __shared__ float  v_s[D_];           // 2 KB
    __shared__ float2 part[4][256];      // 8 KB
    __shared__ float2 wred[4];
    __shared__ float  a_s[TB][256];      // 2 KB
    __shared__ float  mixp[4][TB][D_];   // 16 KB

    if (tid < 512) {
        w_s[0][tid] = wqs[(size_t)(b * T_ + t0 + 0) * D_ + tid];
        w_s[1][tid] = wqs[(size_t)(b * T_ + t0 + 1) * D_ + tid];
        v_s[tid]    = v[tid];
    }
    __syncthreads();

    // 4 independent accumulator chains (j even/odd x t) for fma-latency ILP
    float a0e = 0.f, a0o = 0.f, a1e = 0.f, a1o = 0.f;
    const int dd0 = h * 16;
    const uint4* u4 = (const uint4*)(uhb + ((size_t)(b * 64 + dd0) * 256 + s) * 8);

    #pragma unroll 4
    for (int dd = 0; dd < 16; ++dd) {
        uint4 uu = u4[(size_t)dd * 256];
        float uf[8];
        uf[0] = asf(uu.x << 16); uf[1] = asf(uu.x & 0xffff0000u);
        uf[2] = asf(uu.y << 16); uf[3] = asf(uu.y & 0xffff0000u);
        uf[4] = asf(uu.z << 16); uf[5] = asf(uu.z & 0xffff0000u);
        uf[6] = asf(uu.w << 16); uf[7] = asf(uu.w & 0xffff0000u);

        const int dbase = (dd0 + dd) * 8;
        #pragma unroll
        for (int j = 0; j < 8; j += 2) {
            float vv0 = v_s[dbase + j],     vv1 = v_s[dbase + j + 1];
            float x0e = w_s[0][dbase + j] + uf[j];
            float x0o = w_s[0][dbase + j + 1] + uf[j + 1];
            float x1e = w_s[1][dbase + j] + uf[j];
            float x1o = w_s[1][dbase + j + 1] + uf[j + 1];
            float r0e = __builtin_amdgcn_rcpf(__builtin_amdgcn_exp2f(x0e) + 1.0f);
            float r0o = __builtin_amdgcn_rcpf(__builtin_amdgcn_exp2f(x0o) + 1.0f);
            float r1e = __builtin_amdgcn_rcpf(__builtin_amdgcn_exp2f(x1e) + 1.0f);
            float r1o = __builtin_amdgcn_rcpf(__builtin_amdgcn_exp2f(x1o) + 1.0f);
            a0e = fmaf(vv0, r0e, a0e);
            a0o = fmaf(vv1, r0o, a0o);
            a1e = fmaf(vv0, r1e, a1e);
            a1o = fmaf(vv1, r1o, a1o);
        }
    }
    part[h][s] = make_float2(a0e + a0o, a1e + a1o);
    __syncthreads();

    float p0 = 0.f, p1 = 0.f;
    if (tid < 256) {
        float A0 = part[0][tid].x + part[1][tid].x + part[2][tid].x + part[3][tid].x;
        float A1 = part[0][tid].y + part[1][tid].y + part[2][tid].y + part[3][tid].y;
        float keep = 1.0f - (float)mask[b * S_ + tid];
        p0 = __builtin_amdgcn_exp2f(-C2F * A0) * keep;
        p1 = __builtin_amdgcn_exp2f(-C2F * A1) * keep;
        float s0 = p0, s1 = p1;
        #pragma unroll
        for (int off = 1; off < 64; off <<= 1) {
            s0 += __shfl_xor(s0, off);
            s1 += __shfl_xor(s1, off);
        }
        if ((tid & 63) == 0) wred[tid >> 6] = make_float2(s0, s1);
    }
    __syncthreads();

    if (tid < 256) {
        float den0 = wred[0].x + wred[1].x + wred[2].x + wred[3].x;
        float den1 = wred[0].y + wred[1].y + wred[2].y + wred[3].y;
        float a0 = p0 * __builtin_amdgcn_rcpf(den0);
        float a1 = p1 * __builtin_amdgcn_rcpf(den1);
        attn_out[(size_t)(b * T_ + t0 + 0) * S_ + tid] = a0;
        attn_out[(size_t)(b * T_ + t0 + 1) * S_ + tid] = a1;
        a_s[0][tid] = a0;
        a_s[1][tid] = a1;
    }
    __syncthreads();

    const int d2 = tid & 255;
    const int sh = h * 64;
    const unsigned short* cw = CWb + ((size_t)(b * S_) + sh) * D_ + 2 * d2;
    float m[TB][2] = {};
    #pragma unroll 8
    for (int s2 = 0; s2 < 64; ++s2) {
        unsigned int cc = *(const unsigned int*)(cw + (size_t)s2 * D_);
        float c0 = asf(cc << 16), c1 = asf(cc & 0xffff0000u);
        #pragma unroll
        for (int t = 0; t < TB; ++t) {
            float a = a_s[t][sh + s2];
            m[t][0] = fmaf(a, c0, m[t][0]);
            m[t][1] = fmaf(a, c1, m[t][1]);
        }
    }
    #pragma unroll
    for (int t = 0; t < TB; ++t) {
        mixp[h][t][2 * d2]     = m[t][0];
        mixp[h][t][2 * d2 + 1] = m[t][1];
    }
    __syncthreads();

    {
        const int t = tid >> 9, d = tid & 511;
        size_t idx = (size_t)(b * T_ + t0 + t) * D_ + d;
        out[idx] = mixp[0][t][d] + mixp[1][t][d] + mixp[2][t][d] + mixp[3][t][d]
                 + OB[idx];
    }
}

extern "C" void kernel_launch(void* const* d_in, const int* in_sizes, int n_in,
                              void* d_out, int out_size, void* d_ws, size_t ws_size,
                              hipStream_t stream) {
    const float* output  = (const float*)d_in[0];
    const float* context = (const float*)d_in[1];
    const int*   mask    = (const int*)d_in[2];
    const float* Wq      = (const float*)d_in[3];
    const float* bq      = (const float*)d_in[4];
    const float* Wc      = (const float*)d_in[5];
    const float* v       = (const float*)d_in[6];
    const float* Wout    = (const float*)d_in[7];
    const float* bout    = (const float*)d_in[8];

    float* out  = (float*)d_out;                       // (B,T,D)
    float* attn = out + (size_t)B_ * T_ * D_;          // (B,T,S)

    char* ws = (char*)d_ws;
    float* wqs           = (float*)ws;                              // 2 MB
    float* OB            = (float*)(ws + (2u << 20));               // 2 MB
    unsigned short* uhb  = (unsigned short*)(ws + (4u << 20));      // 1 MB
    unsigned short* CWb  = (unsigned short*)(ws + (5u << 20));      // 1 MB
    unsigned short* outb = (unsigned short*)(ws + (6u << 20));      // 1 MB
    unsigned short* ctxb = (unsigned short*)(ws + (7u << 20));      // 1 MB
    unsigned short* Wqb  = (unsigned short*)(ws + (8u << 20));      // 0.5 MB
    unsigned short* Wcb  = (unsigned short*)(ws + (8u << 20) + (512u << 10));
    unsigned short* Woutb= (unsigned short*)(ws + (9u << 20));      // 1 MB

    // 1) fp32 -> bf16 conversion of all GEMM inputs (halves GEMM traffic)
    CV cvo = { output,  outb,  B_ * T_ * D_ };
    CV cvc = { context, ctxb,  B_ * S_ * D_ };
    CV cvq = { Wq,      Wqb,   D_ * D_ };
    CV cvw = { Wc,      Wcb,   D_ * D_ };
    CV cvt = { Wout,    Woutb, 2 * D_ * D_ };
    convk<<<dim3(512, 1, 5), dim3(256), 0, stream>>>(cvo, cvc, cvq, cvw, cvt);

    // 2) all four GEMMs, one dispatch, bf16 inputs
    G4 gwq = { outb, Wqb,     0, bq,      wqs, 1 };
    G4 guh = { ctxb, Wcb,     0, nullptr, uhb, 3 };
    G4 gob = { outb, Woutb, 512, bout,    OB,  4 };
    G4 gcw = { ctxb, Woutb,   0, nullptr, CWb, 5 };
    gemm4b<<<dim3(512), dim3(1024), 0, stream>>>(gwq, guh, gob, gcw);

    // 3) fused score + softmax + out-projection
    attn_fused<<<dim3(B_ * T_ / TB), dim3(1024), 0, stream>>>(
        wqs, uhb, CWb, OB, mask, v, attn, out);
}